// Round 6
// baseline (136.260 us; speedup 1.0000x reference)
//
#include <hip/hip_runtime.h>
#include <hip/hip_bf16.h>

#define B_ 8
#define D_ 128
#define S_ 4096

typedef short short8 __attribute__((ext_vector_type(8)));
typedef float f32x4  __attribute__((ext_vector_type(4)));
typedef float f32x16 __attribute__((ext_vector_type(16)));
typedef unsigned int uint;
typedef uint uint4v __attribute__((ext_vector_type(4)));

#define EXP2F(x) exp2f(x)

__device__ __forceinline__ short f2bf(float f) {
    __hip_bfloat16 h = __float2bfloat16(f);
    return *reinterpret_cast<short*>(&h);
}

// pack two f32 -> one u32 of 2 bf16 (elem0 = lo word)
__device__ __forceinline__ uint cvtpk(float lo, float hi) {
    uint r;
    asm("v_cvt_pk_bf16_f32 %0, %1, %2" : "=v"(r) : "v"(lo), "v"(hi));
    return r;
}

// async global->LDS DMA, 16B/lane; LDS dest = wave-uniform base + lane*16
__device__ __forceinline__ void gload16(const void* g, void* l) {
    __builtin_amdgcn_global_load_lds(
        (const __attribute__((address_space(1))) void*)g,
        (__attribute__((address_space(3))) void*)l, 16, 0, 0);
}

// ---------------------------------------------------------------------------
// Kernel 0: pack Wq/Wk/Wv into bf16 MFMA fragments (16x16x32 layout for qkv).
// ---------------------------------------------------------------------------
__global__ __launch_bounds__(256) void wpack_kernel(
    const float* __restrict__ Wq, const float* __restrict__ Wk,
    const float* __restrict__ Wv, short* __restrict__ Wf)
{
    int g = blockIdx.x * 256 + threadIdx.x;      // 0..6143
    int lane = g & 63, kc = (g >> 6) & 3, n = (g >> 8) & 7, wm = g >> 11;
    const float* W = (wm == 0) ? Wq : (wm == 1) ? Wk : Wv;
    int row = n * 16 + (lane & 15);
    int col = kc * 32 + (lane >> 4) * 8;
    short8 o;
    #pragma unroll
    for (int j = 0; j < 8; ++j) o[j] = f2bf(W[row * 128 + col + j]);
    *((short8*)Wf + g) = o;
}

// ---------------------------------------------------------------------------
// Kernel 1: QKV projection via bf16 MFMA (16x16x32), unchanged.
// Q: (B,S,D) bf16 scaled by log2(e)/sqrt(D). K: (B,S,D). V: (B,D,S).
// ---------------------------------------------------------------------------
__global__ __launch_bounds__(256) void qkv_kernel(
    const float* __restrict__ x, const short* __restrict__ Wf,
    const float* __restrict__ bq, const float* __restrict__ bk,
    const float* __restrict__ bv,
    short* __restrict__ Qo, short* __restrict__ Ko, short* __restrict__ Vo)
{
    __shared__ float xt[64 * 132];
    const int b  = blockIdx.y;
    const int s0 = blockIdx.x * 64;
    const int t  = threadIdx.x;
    const int w    = t >> 6;
    const int lane = t & 63;
    const int lr   = lane & 15;
    const int lg   = lane >> 4;

    const float* xb = x + (size_t)b * D_ * S_;
    #pragma unroll
    for (int it = 0; it < 32; ++it) {
        int d = it * 4 + (t >> 6);
        int s = t & 63;
        xt[s * 132 + d] = xb[(size_t)d * S_ + s0 + s];
    }
    __syncthreads();

    short8 xtf[4];
    {
        const float* base = &xt[(w * 16 + lr) * 132 + lg * 8];
        #pragma unroll
        for (int kc = 0; kc < 4; ++kc) {
            float4 a = *(const float4*)(base + kc * 32);
            float4 c = *(const float4*)(base + kc * 32 + 4);
            short8 f;
            f[0] = f2bf(a.x); f[1] = f2bf(a.y); f[2] = f2bf(a.z); f[3] = f2bf(a.w);
            f[4] = f2bf(c.x); f[5] = f2bf(c.y); f[6] = f2bf(c.z); f[7] = f2bf(c.w);
            xtf[kc] = f;
        }
    }

    const float qs = 0.08838834764831845f * 1.4426950408889634f;
    const short8* W8 = (const short8*)Wf;
    const size_t bSD = (size_t)b * S_ * D_;
    const size_t bDS = (size_t)b * D_ * S_;

    #pragma unroll
    for (int n = 0; n < 8; ++n) {
        f32x4 aq = (f32x4){0.f, 0.f, 0.f, 0.f};
        f32x4 ak = (f32x4){0.f, 0.f, 0.f, 0.f};
        f32x4 av = (f32x4){0.f, 0.f, 0.f, 0.f};
        #pragma unroll
        for (int kc = 0; kc < 4; ++kc) {
            short8 wq = W8[(      n * 4 + kc) * 64 + lane];
            short8 wk = W8[(32  + n * 4 + kc) * 64 + lane];
            short8 wv = W8[(64  + n * 4 + kc) * 64 + lane];
            aq = __builtin_amdgcn_mfma_f32_16x16x32_bf16(xtf[kc], wq, aq, 0, 0, 0);
            ak = __builtin_amdgcn_mfma_f32_16x16x32_bf16(xtf[kc], wk, ak, 0, 0, 0);
            av = __builtin_amdgcn_mfma_f32_16x16x32_bf16(wv, xtf[kc], av, 0, 0, 0);
        }
        int e = n * 16 + lr;
        float bqe = bq[e], bke = bk[e];
        #pragma unroll
        for (int r = 0; r < 4; ++r) {
            size_t off = (bSD + (size_t)(s0 + w * 16 + lg * 4 + r) * D_) + e;
            Qo[off] = f2bf((aq[r] + bqe) * qs);
            Ko[off] = f2bf(ak[r] + bke);
        }
        #pragma unroll
        for (int r = 0; r < 4; ++r) {
            int ev = n * 16 + lg * 4 + r;
            Vo[bDS + (size_t)ev * S_ + s0 + w * 16 + lr] = f2bf(av[r] + bv[ev]);
        }
    }
}

// ---------------------------------------------------------------------------
// Kernel 2: flash attention, TWO INDEPENDENT BLOCKS PER CU.
// 512 blocks x 256 threads: 4 waves = 2 kv-halves x 2 q-strips (64 q/block),
// KVBLK=32, K+V staged in LDS via global_load_lds (coalesced, XOR-swizzled,
// double-buffered, 1 block-barrier/tile). 66KB LDS/block -> 2 blocks/CU, so
// each SIMD hosts one wave from each of two blocks with INDEPENDENT barrier
// groups: their phases drift, so one wave's softmax VALU fills the other's
// MFMA-chain stalls (the R0..R5 plateau was 2 phase-locked waves/SIMD; the
// compiler provably won't interleave QK with softmax inside one wave).
// C/D layout (m74/m101): col=lane&31, row=(reg&3)+8*(reg>>2)+4*(lane>>5).
// ---------------------------------------------------------------------------
__global__ __launch_bounds__(256, 2) void attn_kernel(
    const short* __restrict__ Q, const short* __restrict__ K,
    const short* __restrict__ Vt, const float* __restrict__ x,
    float* __restrict__ out)
{
    extern __shared__ __align__(16) char smem[];   // 66048 B
    const int lin = blockIdx.x;
    const int b   = lin & 7;            // XCD swizzle: one b per XCD
    const int q0  = (lin >> 3) * 64;
    const int tid  = threadIdx.x;
    const int w    = tid >> 6;
    const int lane = tid & 63;
    const int q    = lane & 31;         // this lane's q column
    const int hi   = lane >> 5;
    const int half = w >> 1;            // KV half: rows half*2048 .. +2047
    const int ww   = w & 1;             // q strip (q0 + ww*32 ..)

    const size_t bSD = (size_t)b * S_ * D_;

    // Q fragments: qf[c][j] = Q[q0+ww*32+q][c*16 + hi*8 + j]
    short8 qf[8];
    {
        const short* Qrow = Q + bSD + (size_t)(q0 + ww * 32 + q) * D_ + hi * 8;
        #pragma unroll
        for (int c = 0; c < 8; ++c)
            qf[c] = *(const short8*)(Qrow + c * 16);
    }

    f32x16 o[4];
    #pragma unroll
    for (int dt = 0; dt < 4; ++dt)
        #pragma unroll
        for (int i = 0; i < 16; ++i) o[dt][i] = 0.f;
    float m = -1e30f, lsum = 0.f;

    const short* Kb = K + bSD;
    const short* Vb = Vt + (size_t)b * D_ * S_;
    const int kvbase = half * 2048;

    // Per-half LDS: K dbuf 2x8KB, V dbuf 2x8KB.
    char* const Kbase = smem + half * 32768;
    char* const Vbase = Kbase + 16384;

    // DMA staging: each of the half's 2 waves stages 4KB of K + 4KB of V.
    // LDS dest linear; global src pre-swizzled.
    // K tile: 32 rows x 256B; phys 16B-chunk c of row r holds logical c^(r&7).
    auto stageK = [&](int kt, char* Kd) {
        const short* Kg = Kb + (size_t)(kvbase + kt * 32) * D_;
        #pragma unroll
        for (int i = 0; i < 4; ++i) {
            int ki = ww * 4 + i;                 // 1KB chunk: rows 4ki..4ki+3
            int r  = ki * 4 + (lane >> 4);
            gload16(Kg + r * D_ + (((lane & 15) ^ (r & 7)) * 8), Kd + ki * 1024);
        }
    };
    // V tile: 128 d-rows x 64B; phys 16B-chunk c of row r holds c^((r>>1)&3).
    auto stageV = [&](int kt, char* Vd) {
        const short* Vg = Vb + kvbase + kt * 32;
        #pragma unroll
        for (int i = 0; i < 4; ++i) {
            int vi = ww * 4 + i;                 // 1KB chunk: rows 16vi..16vi+15
            int r  = vi * 16 + (lane >> 2);
            gload16(Vg + (size_t)r * S_ + (((lane & 3) ^ ((lane >> 3) & 3)) * 8),
                    Vd + vi * 1024);
        }
    };

    auto tilebody = [&](const char* Kh, const char* Vh) {
        // ---- S^T = K Q^T : acc[r] = S[k = (r&3)+8*(r>>2)+4*hi][q] ----
        f32x16 acc;
        #pragma unroll
        for (int i = 0; i < 16; ++i) acc[i] = 0.f;
        __builtin_amdgcn_s_setprio(1);
        #pragma unroll
        for (int c = 0; c < 8; ++c) {
            short8 kf = *(const short8*)(Kh + q * 256
                          + (((c * 2 + hi) ^ (q & 7)) * 16));
            acc = __builtin_amdgcn_mfma_f32_32x32x16_bf16(kf, qf[c], acc, 0, 0, 0);
        }
        __builtin_amdgcn_s_setprio(0);

        // ---- lane-local online softmax (exp2 domain), defer-max (T13) ----
        float t0 = fmaxf(acc[0],  acc[1]),  t1 = fmaxf(acc[2],  acc[3]);
        float t2 = fmaxf(acc[4],  acc[5]),  t3 = fmaxf(acc[6],  acc[7]);
        float t4 = fmaxf(acc[8],  acc[9]),  t5 = fmaxf(acc[10], acc[11]);
        float t6 = fmaxf(acc[12], acc[13]), t7 = fmaxf(acc[14], acc[15]);
        float tm = fmaxf(fmaxf(fmaxf(t0, t1), fmaxf(t2, t3)),
                         fmaxf(fmaxf(t4, t5), fmaxf(t6, t7)));
        tm = fmaxf(tm, __shfl_xor(tm, 32));
        if (!__all(tm <= m + 8.f)) {
            float mn   = fmaxf(m, tm);
            float corr = EXP2F(m - mn);
            m = mn; lsum *= corr;
            #pragma unroll
            for (int dt = 0; dt < 4; ++dt)
                #pragma unroll
                for (int r = 0; r < 16; ++r) o[dt][r] *= corr;
        }
        #pragma unroll
        for (int r = 0; r < 16; ++r) acc[r] = EXP2F(acc[r] - m);
        float s0 = ((acc[0]+acc[1])+(acc[2]+acc[3]))
                 + ((acc[4]+acc[5])+(acc[6]+acc[7]));
        float s1 = ((acc[8]+acc[9])+(acc[10]+acc[11]))
                 + ((acc[12]+acc[13])+(acc[14]+acc[15]));
        float ps = s0 + s1;
        ps += __shfl_xor(ps, 32);
        lsum += ps;

        // ---- P -> bf16 PV B-fragments (distinct SSA defs -> permlane safe) --
        short8 pf[2];
        #pragma unroll
        for (int kc = 0; kc < 2; ++kc) {
            int c1 = kc * 8;
            uint W0 = cvtpk(acc[c1 + 0], acc[c1 + 1]);   // k: 4hi+{0,1}
            uint W1 = cvtpk(acc[c1 + 2], acc[c1 + 3]);   // k: 4hi+{2,3}
            uint W2 = cvtpk(acc[c1 + 4], acc[c1 + 5]);   // k: 8+4hi+{0,1}
            uint W3 = cvtpk(acc[c1 + 6], acc[c1 + 7]);   // k: 8+4hi+{2,3}
            asm("v_permlane32_swap_b32 %0, %1" : "+v"(W0), "+v"(W2));
            asm("v_permlane32_swap_b32 %0, %1" : "+v"(W1), "+v"(W3));
            uint4v pw;
            pw.x = W0;   // k 8hi+{0,1}
            pw.y = W1;   // k 8hi+{2,3}
            pw.z = W2;   // k 8hi+{4,5}
            pw.w = W3;   // k 8hi+{6,7}
            pf[kc] = *reinterpret_cast<short8*>(&pw);
        }

        // ---- O^T += V^T P^T ----
        __builtin_amdgcn_s_setprio(1);
        #pragma unroll
        for (int kc = 0; kc < 2; ++kc)
            #pragma unroll
            for (int dt = 0; dt < 4; ++dt) {
                int row = dt * 32 + q;
                short8 vf = *(const short8*)(Vh + row * 64
                              + (((kc * 2 + hi) ^ ((row >> 1) & 3)) * 16));
                o[dt] = __builtin_amdgcn_mfma_f32_32x32x16_bf16(vf, pf[kc], o[dt], 0, 0, 0);
            }
        __builtin_amdgcn_s_setprio(0);
    };

    // Prologue
    stageK(0, Kbase); stageV(0, Vbase);
    __syncthreads();
    int cur = 0;

    for (int kt = 0; kt < 63; ++kt) {
        stageK(kt + 1, Kbase + (cur ^ 1) * 8192);
        stageV(kt + 1, Vbase + (cur ^ 1) * 8192);
        tilebody(Kbase + cur * 8192, Vbase + cur * 8192);
        __syncthreads();   // peers' reads of buf[cur] done + DMA drained
        cur ^= 1;
    }
    tilebody(Kbase + cur * 8192, Vbase + cur * 8192);   // tile 63, no stage

    // ---- merge halves through LDS, residual-fused transposed writeout ----
    __syncthreads();
    float2* ml = (float2*)(smem + 65536);
    if (half == 1) {
        float* obuf = (float*)(smem + ww * 16384);
        #pragma unroll
        for (int dt = 0; dt < 4; ++dt)
            #pragma unroll
            for (int r = 0; r < 16; ++r) {
                int dl = dt * 32 + (r & 3) + 8 * (r >> 2) + 4 * hi;
                obuf[dl * 32 + q] = o[dt][r];
            }
        if (hi == 0) {
            float2 v2; v2.x = m; v2.y = lsum;
            ml[ww * 32 + q] = v2;
        }
    }
    __syncthreads();
    if (half == 0) {
        const float* obuf = (const float*)(smem + ww * 16384);
        float2 p = ml[ww * 32 + q];
        float m2 = p.x, l2 = p.y;
        float M  = fmaxf(m, m2);
        float c1 = EXP2F(m - M), c2 = EXP2F(m2 - M);
        float inv = 1.0f / (lsum * c1 + l2 * c2);
        const float* xb = x   + (size_t)b * D_ * S_;
        float*       ob = out + (size_t)b * D_ * S_;
        int s = q0 + ww * 32 + q;
        #pragma unroll
        for (int dt = 0; dt < 4; ++dt)
            #pragma unroll
            for (int r = 0; r < 16; ++r) {
                int dl = dt * 32 + (r & 3) + 8 * (r >> 2) + 4 * hi;
                float val = (o[dt][r] * c1 + obuf[dl * 32 + q] * c2) * inv;
                size_t g = (size_t)dl * S_ + s;
                ob[g] = xb[g] + val;
            }
    }
}

extern "C" void kernel_launch(void* const* d_in, const int* in_sizes, int n_in,
                              void* d_out, int out_size, void* d_ws, size_t ws_size,
                              hipStream_t stream) {
    const float* x  = (const float*)d_in[0];
    const float* Wq = (const float*)d_in[1];
    const float* bq = (const float*)d_in[2];
    const float* Wk = (const float*)d_in[3];
    const float* bk = (const float*)d_in[4];
    const float* Wv = (const float*)d_in[5];
    const float* bv = (const float*)d_in[6];
    float* out = (float*)d_out;

    size_t n = (size_t)B_ * S_ * D_;
    short* Qw = (short*)d_ws;
    short* Kw = Qw + n;
    short* Vw = Kw + n;
    short* Wf = (short*)d_out;   // scratch at head of d_out; fully overwritten

    wpack_kernel<<<24, 256, 0, stream>>>(Wq, Wk, Wv, Wf);

    dim3 grid(S_ / 64, B_);
    qkv_kernel<<<grid, 256, 0, stream>>>(x, Wf, bq, bk, bv, Qw, Kw, Vw);

    int smemB = 66048;
    (void)hipFuncSetAttribute((const void*)attn_kernel,
                              hipFuncAttributeMaxDynamicSharedMemorySize, smemB);
    attn_kernel<<<512, 256, smemB, stream>>>(Qw, Kw, Vw, x, out);
}